// Round 1
// baseline (238.627 us; speedup 1.0000x reference)
//
#include <hip/hip_runtime.h>
#include <hip/hip_bf16.h>

// Problem constants (fixed by the reference).
#define NN 65536
#define DD 512
#define NUM_LABELS 512
#define NUM_DEMOG 4
#define GG (NUM_DEMOG * NUM_LABELS)   // 2048 groups
#define CAP 128                       // bucket capacity; counts ~Binom(65536,1/2048), mean 32

// ---------------------------------------------------------------------------
// K1: histogram + bucket scatter. pos = atomicAdd(cnt[seg]) gives within-group
// rank directly; fixed CAP per group removes the need for a prefix-scan pass.
// ---------------------------------------------------------------------------
__global__ void k_hist(const int* __restrict__ labels,
                       const int* __restrict__ demog,
                       int* __restrict__ cnt,
                       int* __restrict__ order) {
    int i = blockIdx.x * blockDim.x + threadIdx.x;
    if (i >= NN) return;
    int seg = demog[i] * NUM_LABELS + labels[i];
    int pos = atomicAdd(&cnt[seg], 1);
    if (pos < CAP) order[seg * CAP + pos] = i;
}

// ---------------------------------------------------------------------------
// K2: one block per group. Gather rows, accumulate column sums (float4 per
// thread -> 128 threads cover D=512) and sum of squares in registers.
// grp_mean_dist = (sum||x||^2 - ||sum x||^2 / c) / c   (exact algebra, no 2nd
// pass over feats). Fold into per-demog accumulators with 2 atomics/block.
// ---------------------------------------------------------------------------
__global__ __launch_bounds__(128)
void k_group(const float* __restrict__ feats,
             const int* __restrict__ cnt,
             const int* __restrict__ order,
             float* __restrict__ sumA,
             int* __restrict__ presentCnt) {
    int g = blockIdx.x;
    int t = threadIdx.x;

    __shared__ int sidx[CAP];
    int c = cnt[g];
    if (c > CAP) c = CAP;          // paranoia; statistically unreachable
    if (t < c) sidx[t] = order[g * CAP + t];
    __syncthreads();

    const float4* fv = (const float4*)feats;  // row = 128 float4s
    float4 acc = make_float4(0.f, 0.f, 0.f, 0.f);
    float ssq = 0.f;
    for (int j = 0; j < c; ++j) {
        float4 v = fv[(size_t)sidx[j] * (DD / 4) + t];
        acc.x += v.x; acc.y += v.y; acc.z += v.z; acc.w += v.w;
        ssq += v.x * v.x + v.y * v.y + v.z * v.z + v.w * v.w;
    }
    float n2 = acc.x * acc.x + acc.y * acc.y + acc.z * acc.z + acc.w * acc.w;

    // Reduce ssq and n2 across 128 threads: wave64 shuffle, then 2 waves via LDS.
    for (int off = 32; off > 0; off >>= 1) {
        ssq += __shfl_down(ssq, off);
        n2  += __shfl_down(n2,  off);
    }
    __shared__ float red[4];
    if ((t & 63) == 0) {
        red[(t >> 6) * 2]     = ssq;
        red[(t >> 6) * 2 + 1] = n2;
    }
    __syncthreads();
    if (t == 0 && c > 0) {
        float S  = red[0] + red[2];
        float N2 = red[1] + red[3];
        float gm = (S - N2 / (float)c) / (float)c;
        int dgr = g >> 9;   // g / NUM_LABELS
        atomicAdd(&sumA[dgr], gm);
        atomicAdd(&presentCnt[dgr], 1);
    }
}

// ---------------------------------------------------------------------------
// K3: final 4-element reduction -> scalar loss.
// ---------------------------------------------------------------------------
__global__ void k_final(const float* __restrict__ sumA,
                        const int* __restrict__ presentCnt,
                        float* __restrict__ out) {
    if (threadIdx.x == 0 && blockIdx.x == 0) {
        float intra[NUM_DEMOG];
        float m = 0.f;
        for (int d = 0; d < NUM_DEMOG; ++d) {
            float p = (float)presentCnt[d];
            intra[d] = sumA[d] / fmaxf(p, 1.f);
            m += intra[d];
        }
        m *= (1.f / NUM_DEMOG);
        float l = 0.f;
        for (int d = 0; d < NUM_DEMOG; ++d) l += fabsf(intra[d] - m);
        out[0] = l * (1.f / NUM_DEMOG);
    }
}

extern "C" void kernel_launch(void* const* d_in, const int* in_sizes, int n_in,
                              void* d_out, int out_size, void* d_ws, size_t ws_size,
                              hipStream_t stream) {
    const float* feats = (const float*)d_in[0];
    const int* labels  = (const int*)d_in[1];
    const int* demog   = (const int*)d_in[2];
    float* out = (float*)d_out;

    // Workspace layout (ints unless noted):
    //   [0, 2048)        cnt[G]
    //   [2048, 2052)     presentCnt[4]
    //   [2052, 2056)     sumA[4] (float)
    //   [2056, ...)      order[G*CAP]  (1 MiB)
    int*   cnt        = (int*)d_ws;
    int*   presentCnt = cnt + GG;
    float* sumA       = (float*)(cnt + GG + NUM_DEMOG);
    int*   order      = cnt + GG + 2 * NUM_DEMOG;

    // Zero cnt + accumulators (ws is poisoned 0xAA before each timed launch).
    hipMemsetAsync(d_ws, 0, (GG + 2 * NUM_DEMOG) * sizeof(int), stream);

    k_hist<<<NN / 256, 256, 0, stream>>>(labels, demog, cnt, order);
    k_group<<<GG, 128, 0, stream>>>(feats, cnt, order, sumA, presentCnt);
    k_final<<<1, 64, 0, stream>>>(sumA, presentCnt, out);
}

// Round 2
// 231.442 us; speedup vs baseline: 1.0310x; 1.0310x over previous
//
#include <hip/hip_runtime.h>
#include <hip/hip_bf16.h>

// Problem constants (fixed by the reference).
#define NN 65536
#define DD 512
#define NUM_LABELS 512
#define NUM_DEMOG 4
#define GG (NUM_DEMOG * NUM_LABELS)   // 2048 groups
#define CAP 128                       // counts ~Binom(65536,1/2048), mean 32; 128 = ~17 sigma

// ---------------------------------------------------------------------------
// K1: histogram + bucket scatter (rank via atomicAdd; no prefix-scan pass).
// ---------------------------------------------------------------------------
__global__ void k_hist(const int* __restrict__ labels,
                       const int* __restrict__ demog,
                       int* __restrict__ cnt,
                       int* __restrict__ order) {
    int i = blockIdx.x * blockDim.x + threadIdx.x;
    if (i >= NN) return;
    int seg = demog[i] * NUM_LABELS + labels[i];
    int pos = atomicAdd(&cnt[seg], 1);
    if (pos < CAP) order[seg * CAP + pos] = i;
}

// ---------------------------------------------------------------------------
// K2: one 256-thread block per group. col = t&127 (one float4 of the row),
// rp = t>>7 (2 rows in flight). Manual 4x row unroll -> 4 independent loads
// in flight per thread before the accumulate chain (latency hiding).
// gm = (sum||x||^2 - ||sum x||^2/c)/c  -- exact, single pass over feats.
// ---------------------------------------------------------------------------
__global__ __launch_bounds__(256)
void k_group(const float* __restrict__ feats,
             const int* __restrict__ cnt,
             const int* __restrict__ order,
             float* __restrict__ sumA,
             int* __restrict__ presentCnt) {
    int g = blockIdx.x;
    int t = threadIdx.x;
    int col = t & 127;
    int rp  = t >> 7;

    __shared__ int sidx[CAP];
    int c = cnt[g];
    if (c > CAP) c = CAP;          // statistically unreachable
    if (t < c) sidx[t] = order[g * CAP + t];
    __syncthreads();

    const float4* fv = (const float4*)feats;  // row = 128 float4s
    float4 acc = make_float4(0.f, 0.f, 0.f, 0.f);
    float ssq = 0.f;

    int j = rp;
    // 4 rows per iteration for this thread (stride 2 between rp partners).
    for (; j + 6 < c; j += 8) {
        int i0 = sidx[j], i1 = sidx[j + 2], i2 = sidx[j + 4], i3 = sidx[j + 6];
        float4 v0 = fv[(size_t)i0 * (DD / 4) + col];
        float4 v1 = fv[(size_t)i1 * (DD / 4) + col];
        float4 v2 = fv[(size_t)i2 * (DD / 4) + col];
        float4 v3 = fv[(size_t)i3 * (DD / 4) + col];
        acc.x += v0.x + v1.x + v2.x + v3.x;
        acc.y += v0.y + v1.y + v2.y + v3.y;
        acc.z += v0.z + v1.z + v2.z + v3.z;
        acc.w += v0.w + v1.w + v2.w + v3.w;
        ssq += v0.x * v0.x + v0.y * v0.y + v0.z * v0.z + v0.w * v0.w;
        ssq += v1.x * v1.x + v1.y * v1.y + v1.z * v1.z + v1.w * v1.w;
        ssq += v2.x * v2.x + v2.y * v2.y + v2.z * v2.z + v2.w * v2.w;
        ssq += v3.x * v3.x + v3.y * v3.y + v3.z * v3.z + v3.w * v3.w;
    }
    for (; j < c; j += 2) {
        float4 v = fv[(size_t)sidx[j] * (DD / 4) + col];
        acc.x += v.x; acc.y += v.y; acc.z += v.z; acc.w += v.w;
        ssq += v.x * v.x + v.y * v.y + v.z * v.z + v.w * v.w;
    }

    // Combine the rp=0/rp=1 column-sum partials (contiguous b128 -> no bank
    // conflicts), then compute the ||sum x||^2 partial on rp=0 threads.
    __shared__ float4 accbuf[128];
    if (rp == 1) accbuf[col] = acc;
    __syncthreads();
    float n2p = 0.f;
    if (rp == 0) {
        float4 o = accbuf[col];
        float x = acc.x + o.x, y = acc.y + o.y, z = acc.z + o.z, w = acc.w + o.w;
        n2p = x * x + y * y + z * z + w * w;
    }

    // Scalar block reduction: wave shuffle, then 4 waves via LDS.
    for (int off = 32; off > 0; off >>= 1) {
        ssq += __shfl_down(ssq, off);
        n2p += __shfl_down(n2p, off);
    }
    __shared__ float red[8];
    if ((t & 63) == 0) {
        int wid = t >> 6;
        red[wid * 2]     = ssq;
        red[wid * 2 + 1] = n2p;
    }
    __syncthreads();
    if (t == 0 && c > 0) {
        float S  = red[0] + red[2] + red[4] + red[6];
        float N2 = red[1] + red[3] + red[5] + red[7];
        float gm = (S - N2 / (float)c) / (float)c;
        int dgr = g >> 9;   // g / NUM_LABELS
        atomicAdd(&sumA[dgr], gm);
        atomicAdd(&presentCnt[dgr], 1);
    }
}

// ---------------------------------------------------------------------------
// K3: final 4-element reduction -> scalar loss.
// ---------------------------------------------------------------------------
__global__ void k_final(const float* __restrict__ sumA,
                        const int* __restrict__ presentCnt,
                        float* __restrict__ out) {
    if (threadIdx.x == 0 && blockIdx.x == 0) {
        float intra[NUM_DEMOG];
        float m = 0.f;
        for (int d = 0; d < NUM_DEMOG; ++d) {
            float p = (float)presentCnt[d];
            intra[d] = sumA[d] / fmaxf(p, 1.f);
            m += intra[d];
        }
        m *= (1.f / NUM_DEMOG);
        float l = 0.f;
        for (int d = 0; d < NUM_DEMOG; ++d) l += fabsf(intra[d] - m);
        out[0] = l * (1.f / NUM_DEMOG);
    }
}

extern "C" void kernel_launch(void* const* d_in, const int* in_sizes, int n_in,
                              void* d_out, int out_size, void* d_ws, size_t ws_size,
                              hipStream_t stream) {
    const float* feats = (const float*)d_in[0];
    const int* labels  = (const int*)d_in[1];
    const int* demog   = (const int*)d_in[2];
    float* out = (float*)d_out;

    // Workspace layout:
    //   [0, 2048)  cnt[G]  | +4 presentCnt[4] | +4 sumA[4] (float) | order[G*CAP]
    int*   cnt        = (int*)d_ws;
    int*   presentCnt = cnt + GG;
    float* sumA       = (float*)(cnt + GG + NUM_DEMOG);
    int*   order      = cnt + GG + 2 * NUM_DEMOG;

    hipMemsetAsync(d_ws, 0, (GG + 2 * NUM_DEMOG) * sizeof(int), stream);

    k_hist<<<NN / 256, 256, 0, stream>>>(labels, demog, cnt, order);
    k_group<<<GG, 256, 0, stream>>>(feats, cnt, order, sumA, presentCnt);
    k_final<<<1, 64, 0, stream>>>(sumA, presentCnt, out);
}

// Round 3
// 212.009 us; speedup vs baseline: 1.1256x; 1.0917x over previous
//
#include <hip/hip_runtime.h>
#include <hip/hip_bf16.h>

// Problem constants (fixed by the reference).
#define NN 65536
#define DD 512
#define NUM_LABELS 512
#define NUM_DEMOG 4
#define GG (NUM_DEMOG * NUM_LABELS)   // 2048 groups
#define CAP 128                       // counts ~Binom(65536,1/2048), mean 32; 128 = ~17 sigma

// ---------------------------------------------------------------------------
// K1: histogram + bucket scatter (rank via atomicAdd; no prefix-scan pass).
// ---------------------------------------------------------------------------
__global__ void k_hist(const int* __restrict__ labels,
                       const int* __restrict__ demog,
                       int* __restrict__ cnt,
                       int* __restrict__ order) {
    int i = blockIdx.x * blockDim.x + threadIdx.x;
    if (i >= NN) return;
    int seg = demog[i] * NUM_LABELS + labels[i];
    int pos = atomicAdd(&cnt[seg], 1);
    if (pos < CAP) order[seg * CAP + pos] = i;
}

// ---------------------------------------------------------------------------
// K2: one 256-thread block per group. col = t&127, rp = t>>7 (2 row-partners).
// 8 independent float4 loads in flight per thread. NO global atomics: each
// block writes one scalar gm[g]; k_final reduces the 2048-element array.
// gm = (sum||x||^2 - ||sum x||^2/c)/c  -- exact, single pass over feats.
// ---------------------------------------------------------------------------
__global__ __launch_bounds__(256)
void k_group(const float* __restrict__ feats,
             const int* __restrict__ cnt,
             const int* __restrict__ order,
             float* __restrict__ gmArr) {
    int g = blockIdx.x;
    int t = threadIdx.x;
    int col = t & 127;
    int rp  = t >> 7;

    // Issue order-load and cnt-load concurrently (no dependency on c).
    __shared__ int sidx[CAP];
    int oi = (t < CAP) ? order[g * CAP + t] : 0;
    int c = cnt[g];
    if (c > CAP) c = CAP;          // statistically unreachable
    if (t < CAP) sidx[t] = oi;
    __syncthreads();

    const float4* fv = (const float4*)feats;  // row = 128 float4s
    float4 acc = make_float4(0.f, 0.f, 0.f, 0.f);
    float ssq = 0.f;

    int j = rp;
    // 8 rows in flight per thread (rp partners interleave at stride 2).
    for (; j + 14 < c; j += 16) {
        int i0 = sidx[j],      i1 = sidx[j + 2],  i2 = sidx[j + 4],  i3 = sidx[j + 6];
        int i4 = sidx[j + 8],  i5 = sidx[j + 10], i6 = sidx[j + 12], i7 = sidx[j + 14];
        float4 v0 = fv[(size_t)i0 * (DD / 4) + col];
        float4 v1 = fv[(size_t)i1 * (DD / 4) + col];
        float4 v2 = fv[(size_t)i2 * (DD / 4) + col];
        float4 v3 = fv[(size_t)i3 * (DD / 4) + col];
        float4 v4 = fv[(size_t)i4 * (DD / 4) + col];
        float4 v5 = fv[(size_t)i5 * (DD / 4) + col];
        float4 v6 = fv[(size_t)i6 * (DD / 4) + col];
        float4 v7 = fv[(size_t)i7 * (DD / 4) + col];
        acc.x += v0.x + v1.x + v2.x + v3.x + v4.x + v5.x + v6.x + v7.x;
        acc.y += v0.y + v1.y + v2.y + v3.y + v4.y + v5.y + v6.y + v7.y;
        acc.z += v0.z + v1.z + v2.z + v3.z + v4.z + v5.z + v6.z + v7.z;
        acc.w += v0.w + v1.w + v2.w + v3.w + v4.w + v5.w + v6.w + v7.w;
        ssq += v0.x * v0.x + v0.y * v0.y + v0.z * v0.z + v0.w * v0.w;
        ssq += v1.x * v1.x + v1.y * v1.y + v1.z * v1.z + v1.w * v1.w;
        ssq += v2.x * v2.x + v2.y * v2.y + v2.z * v2.z + v2.w * v2.w;
        ssq += v3.x * v3.x + v3.y * v3.y + v3.z * v3.z + v3.w * v3.w;
        ssq += v4.x * v4.x + v4.y * v4.y + v4.z * v4.z + v4.w * v4.w;
        ssq += v5.x * v5.x + v5.y * v5.y + v5.z * v5.z + v5.w * v5.w;
        ssq += v6.x * v6.x + v6.y * v6.y + v6.z * v6.z + v6.w * v6.w;
        ssq += v7.x * v7.x + v7.y * v7.y + v7.z * v7.z + v7.w * v7.w;
    }
    for (; j + 6 < c; j += 8) {
        int i0 = sidx[j], i1 = sidx[j + 2], i2 = sidx[j + 4], i3 = sidx[j + 6];
        float4 v0 = fv[(size_t)i0 * (DD / 4) + col];
        float4 v1 = fv[(size_t)i1 * (DD / 4) + col];
        float4 v2 = fv[(size_t)i2 * (DD / 4) + col];
        float4 v3 = fv[(size_t)i3 * (DD / 4) + col];
        acc.x += v0.x + v1.x + v2.x + v3.x;
        acc.y += v0.y + v1.y + v2.y + v3.y;
        acc.z += v0.z + v1.z + v2.z + v3.z;
        acc.w += v0.w + v1.w + v2.w + v3.w;
        ssq += v0.x * v0.x + v0.y * v0.y + v0.z * v0.z + v0.w * v0.w;
        ssq += v1.x * v1.x + v1.y * v1.y + v1.z * v1.z + v1.w * v1.w;
        ssq += v2.x * v2.x + v2.y * v2.y + v2.z * v2.z + v2.w * v2.w;
        ssq += v3.x * v3.x + v3.y * v3.y + v3.z * v3.z + v3.w * v3.w;
    }
    for (; j < c; j += 2) {
        float4 v = fv[(size_t)sidx[j] * (DD / 4) + col];
        acc.x += v.x; acc.y += v.y; acc.z += v.z; acc.w += v.w;
        ssq += v.x * v.x + v.y * v.y + v.z * v.z + v.w * v.w;
    }

    // Combine rp=0/rp=1 column partials via LDS (contiguous b128, no conflicts).
    __shared__ float4 accbuf[128];
    if (rp == 1) accbuf[col] = acc;
    __syncthreads();
    float n2p = 0.f;
    if (rp == 0) {
        float4 o = accbuf[col];
        float x = acc.x + o.x, y = acc.y + o.y, z = acc.z + o.z, w = acc.w + o.w;
        n2p = x * x + y * y + z * z + w * w;
    }

    // Scalar block reduction: wave shuffle, then 4 waves via LDS.
    for (int off = 32; off > 0; off >>= 1) {
        ssq += __shfl_down(ssq, off);
        n2p += __shfl_down(n2p, off);
    }
    __shared__ float red[8];
    if ((t & 63) == 0) {
        int wid = t >> 6;
        red[wid * 2]     = ssq;
        red[wid * 2 + 1] = n2p;
    }
    __syncthreads();
    if (t == 0) {
        float gm = 0.f;
        if (c > 0) {
            float S  = red[0] + red[2] + red[4] + red[6];
            float N2 = red[1] + red[3] + red[5] + red[7];
            gm = (S - N2 / (float)c) / (float)c;
        }
        gmArr[g] = gm;    // plain store — no atomics anywhere in the epilogue
    }
}

// ---------------------------------------------------------------------------
// K3: reduce gm[G] + cnt[G] -> per-demog intra -> scalar loss. One block.
// ---------------------------------------------------------------------------
__global__ __launch_bounds__(256)
void k_final(const int* __restrict__ cnt,
             const float* __restrict__ gmArr,
             float* __restrict__ out) {
    int t = threadIdx.x;
    __shared__ float sred[8];
    __shared__ float intra[NUM_DEMOG];

    for (int d = 0; d < NUM_DEMOG; ++d) {
        float s = 0.f;
        float p = 0.f;
        for (int l = t; l < NUM_LABELS; l += 256) {
            int g = d * NUM_LABELS + l;
            if (cnt[g] > 0) { s += gmArr[g]; p += 1.f; }
        }
        for (int off = 32; off > 0; off >>= 1) {
            s += __shfl_down(s, off);
            p += __shfl_down(p, off);
        }
        if ((t & 63) == 0) {
            int wid = t >> 6;
            sred[wid * 2]     = s;
            sred[wid * 2 + 1] = p;
        }
        __syncthreads();
        if (t == 0) {
            float S = sred[0] + sred[2] + sred[4] + sred[6];
            float P = sred[1] + sred[3] + sred[5] + sred[7];
            intra[d] = S / fmaxf(P, 1.f);
        }
        __syncthreads();
    }
    if (t == 0) {
        float m = 0.f;
        for (int d = 0; d < NUM_DEMOG; ++d) m += intra[d];
        m *= (1.f / NUM_DEMOG);
        float l = 0.f;
        for (int d = 0; d < NUM_DEMOG; ++d) l += fabsf(intra[d] - m);
        out[0] = l * (1.f / NUM_DEMOG);
    }
}

extern "C" void kernel_launch(void* const* d_in, const int* in_sizes, int n_in,
                              void* d_out, int out_size, void* d_ws, size_t ws_size,
                              hipStream_t stream) {
    const float* feats = (const float*)d_in[0];
    const int* labels  = (const int*)d_in[1];
    const int* demog   = (const int*)d_in[2];
    float* out = (float*)d_out;

    // Workspace layout: cnt[G] int | gm[G] float | order[G*CAP] int
    int*   cnt   = (int*)d_ws;
    float* gmArr = (float*)(cnt + GG);
    int*   order = (int*)(gmArr + GG);

    hipMemsetAsync(d_ws, 0, GG * sizeof(int), stream);  // zero cnt only

    k_hist<<<NN / 256, 256, 0, stream>>>(labels, demog, cnt, order);
    k_group<<<GG, 256, 0, stream>>>(feats, cnt, order, gmArr);
    k_final<<<1, 256, 0, stream>>>(cnt, gmArr, out);
}